// Round 7
// baseline (122.766 us; speedup 1.0000x reference)
//
#include <hip/hip_runtime.h>
#include <hip/hip_bf16.h>

// CARNN: 9-step RNN (D=64) + projection to 300 actions, BATCH=65536.
// R11: W32 geometry. LDS is a PER-CU pipe (shared by 4 SIMDs) -> the RNN
// was DS-instruction-throughput bound: 16 waves x 16 weight b128 reads =
// 256/step/CU. Now each wave owns 32 rows (two 16-row subtiles) sharing
// one weight-fragment set: weight reads halve (128/step/CU), MFMA/VALU
// per CU invariant. 512-thr blocks (8 waves), 256 rows/block, grid 256,
// 1 block/CU, 2 waves/SIMD (VGPR cap 256 -> no spill). Barrier-free RNN
// kept: wave-private XOR-swizzled H (2x2KB per wave), lgkmcnt ordering,
// 3 barriers total. Projection identical structure, two row-sets/wave.

#define SEQ     9
#define DMODEL  64
#define ANUM    300

// ws layout (bf16 element offsets) -- unchanged, prepack identical
#define WS_MW   0        // 9*8192: per step [kind(M=0,W=1)][nt][kb][lane][8]
#define WS_OW   73728    // 5*4096: [cc][nt][kb][lane][8]
#define WS_EMB  94208    // 301*64 bf16 emb table
#define WS_END  113472
#define WS_BSUM_BYTES (WS_END * 2)

// LDS layout (shorts): weights s0M(4096) + s1..7(7*8192) | bsum | scratch
#define BSOFF   61440
#define HSOFF   62592     // 8 waves x 2048 shorts (4KB each: 2 halves x 2KB)
#define SLTOT   78976     // 157,952 bytes

typedef __attribute__((ext_vector_type(8))) short  bf16x8;
typedef __attribute__((ext_vector_type(4))) float  f32x4;

#define MFMA __builtin_amdgcn_mfma_f32_16x16x32_bf16

__device__ __forceinline__ unsigned short f2b(float f) {
    union { float f; unsigned int u; } x; x.f = f;
    unsigned int r = x.u + 0x7FFFu + ((x.u >> 16) & 1u);
    return (unsigned short)(r >> 16);
}

__device__ __forceinline__ float sigmoid_fast(float v) {
    return __builtin_amdgcn_rcpf(1.f + __expf(-v));
}

// async global->LDS, 16 B per lane; lds base must be wave-uniform
__device__ __forceinline__ void async16(const unsigned short* g, unsigned short* l) {
    __builtin_amdgcn_global_load_lds(
        (const __attribute__((address_space(1))) unsigned int*)g,
        (__attribute__((address_space(3))) unsigned int*)l, 16, 0, 0);
}

// ---------------- pre-pass: convert + pack (unchanged) ----------------
#define PP_TOTAL (73728 + 20480 + 19264 + 576)

__global__ void prepack(const float* __restrict__ Mw, const float* __restrict__ Ww,
                        const float* __restrict__ outw, const float* __restrict__ emb,
                        const float* __restrict__ Mb, const float* __restrict__ Wb,
                        unsigned short* __restrict__ wsb, float* __restrict__ bsum)
{
    int t = blockIdx.x * 256 + threadIdx.x;
    if (t < 73728) {                       // M+W, step-major 16KB blocks
        int s    = t >> 13;
        int r    = t & 8191;
        int kind = r >> 12;
        int f    = r & 4095;
        int nt   = f >> 10;
        int kb   = (f >> 9) & 1;
        int lane = (f >> 3) & 63;
        int j    = f & 7;
        int nr   = nt * 16 + (lane & 15);
        int k    = kb * 32 + ((lane >> 4) << 3) + j;
        const float* src = kind ? Ww : Mw;
        wsb[WS_MW + t] = f2b(src[(s * DMODEL + nr) * DMODEL + k]);
        return;
    }
    t -= 73728;
    if (t < 20480) {                       // outw fragments
        int j    = t & 7;
        int lane = (t >> 3) & 63;
        int kb   = (t >> 9) & 1;
        int nt   = (t >> 10) & 3;
        int cc   = t >> 12;
        int col  = cc * 64 + nt * 16 + (lane & 15);
        int k    = kb * 32 + ((lane >> 4) << 3) + j;
        float v  = (col < ANUM) ? outw[col * DMODEL + k] : 0.f;
        wsb[WS_OW + t] = f2b(v);
        return;
    }
    t -= 20480;
    if (t < 19264) { wsb[WS_EMB + t] = f2b(emb[t]); return; }
    t -= 19264;
    if (t < 576)   { bsum[t] = Mb[t] + Wb[t]; }
}

// ---------------- main ----------------
__global__ __launch_bounds__(512, 2)
void carnn_main(const int* __restrict__ acts,
                const unsigned short* __restrict__ wsb,
                const float* __restrict__ bsum,
                const float* __restrict__ outb,
                float* __restrict__ out)
{
    __shared__ __align__(16) unsigned short SL[SLTOT];

    const int tid  = threadIdx.x;
    const int lane = tid & 63;
    const int wv   = tid >> 6;         // 0..7
    const int lrow = lane & 15;        // batch row within subtile
    const int quad = lane >> 4;

    const int brow0 = blockIdx.x * 256 + wv * 32 + lrow;   // subtile 0
    const int brow1 = brow0 + 16;                          // subtile 1
    const int rowS0 = brow0 * SEQ;
    const int rowS1 = brow1 * SEQ;

    // ---- stage weights s0M + s1..7 (120 chunks of 1KB, 15 per wave) ----
    for (int c = wv; c < 120; c += 8) {
        const int goff = (c < 8) ? (c * 512) : ((c + 8) * 512);
        async16(wsb + WS_MW + goff + lane * 8, &SL[c * 512]);
    }
    // ---- stage bsum (2304 B) ----
    {
        const unsigned short* bs = (const unsigned short*)bsum;
        if (wv == 5) async16(bs + lane * 8,        &SL[BSOFF]);
        if (wv == 6) async16(bs + 512 + lane * 8,  &SL[BSOFF + 512]);
        if (wv == 7 && lane < 16)
                     async16(bs + 1024 + lane * 8, &SL[BSOFF + 1024]);
    }

    // step-0 inputs (overlap with staging)
    const unsigned short* Eb = wsb + WS_EMB;
    int idc0 = acts[rowS0], idc1 = acts[rowS1];
    bf16x8 xc00 = *(const bf16x8*)(Eb + idc0 * DMODEL + quad * 8);
    bf16x8 xc01 = *(const bf16x8*)(Eb + idc0 * DMODEL + 32 + quad * 8);
    bf16x8 xc10 = *(const bf16x8*)(Eb + idc1 * DMODEL + quad * 8);
    bf16x8 xc11 = *(const bf16x8*)(Eb + idc1 * DMODEL + 32 + quad * 8);
    int idn0 = acts[rowS0 + 1], idn1 = acts[rowS1 + 1];

    // per-wave H scratch: 2 x 2KB (one per subtile), XOR-swizzled
    char* const SB = (char*)SL;
    const int swz = (lrow & 7) << 4;
    const int hb0 = HSOFF * 2 + wv * 4096 + lrow * 128;        // subtile 0
    const int hb1 = hb0 + 2048;                                // subtile 1
    const int r00 = hb0 + ((quad * 16) ^ swz);
    const int r01 = hb0 + ((64 + quad * 16) ^ swz);
    const int r10 = hb1 + ((quad * 16) ^ swz);
    const int r11 = hb1 + ((64 + quad * 16) ^ swz);

    __syncthreads();    // barrier #1: weights + bsum staged

    const float* BSf = (const float*)&SL[BSOFF];

    #pragma unroll
    for (int s = 0; s < SEQ; ++s) {
        // prefetch next step's x fragments (ids already resident)
        bf16x8 xn00, xn01, xn10, xn11;
        if (s + 1 < SEQ) {
            xn00 = *(const bf16x8*)(Eb + idn0 * DMODEL + quad * 8);
            xn01 = *(const bf16x8*)(Eb + idn0 * DMODEL + 32 + quad * 8);
            xn10 = *(const bf16x8*)(Eb + idn1 * DMODEL + quad * 8);
            xn11 = *(const bf16x8*)(Eb + idn1 * DMODEL + 32 + quad * 8);
            if (s + 2 < SEQ) {
                idn0 = acts[rowS0 + s + 2];
                idn1 = acts[rowS1 + s + 2];
            }
        }
        // previous-step H fragments, both subtiles (wave-private)
        bf16x8 h00, h01, h10, h11;
        if (s > 0) {
            h00 = *(const bf16x8*)(SB + r00);
            h01 = *(const bf16x8*)(SB + r01);
            h10 = *(const bf16x8*)(SB + r10);
            h11 = *(const bf16x8*)(SB + r11);
        }
        // weight fragment base: LDS for s<8, global (L2) for s8
        const unsigned short* WB;
        if (s == 0)     WB = &SL[0];
        else if (s < 8) WB = &SL[4096 + (s - 1) * 8192];
        else            WB = wsb + WS_MW + 8 * 8192;

        #pragma unroll
        for (int nt = 0; nt < 4; ++nt) {
            const unsigned short* Mf = WB + nt * 1024 + lane * 8;
            bf16x8 am0 = *(const bf16x8*)Mf;
            bf16x8 am1 = *(const bf16x8*)(Mf + 512);
            const f32x4 bias = *(const f32x4*)(BSf + s * 64 + nt * 16 + quad * 4);
            f32x4 aA = bias, aB = bias;
            aA = MFMA(am0, xc00, aA, 0, 0, 0);   // A=weights shared by both
            aA = MFMA(am1, xc01, aA, 0, 0, 0);
            aB = MFMA(am0, xc10, aB, 0, 0, 0);
            aB = MFMA(am1, xc11, aB, 0, 0, 0);
            if (s > 0) {
                const unsigned short* Wf = WB + 4096 + nt * 1024 + lane * 8;
                bf16x8 aw0 = *(const bf16x8*)Wf;
                bf16x8 aw1 = *(const bf16x8*)(Wf + 512);
                aA = MFMA(aw0, h00, aA, 0, 0, 0);
                aA = MFMA(aw1, h01, aA, 0, 0, 0);
                aB = MFMA(aw0, h10, aB, 0, 0, 0);
                aB = MFMA(aw1, h11, aB, 0, 0, 0);
            }
            // sigmoid -> bf16 pack -> one b64 write per subtile
            unsigned int a0 = (unsigned int)f2b(sigmoid_fast(aA[0]))
                            | ((unsigned int)f2b(sigmoid_fast(aA[1])) << 16);
            unsigned int a1 = (unsigned int)f2b(sigmoid_fast(aA[2]))
                            | ((unsigned int)f2b(sigmoid_fast(aA[3])) << 16);
            unsigned int b0 = (unsigned int)f2b(sigmoid_fast(aB[0]))
                            | ((unsigned int)f2b(sigmoid_fast(aB[1])) << 16);
            unsigned int b1 = (unsigned int)f2b(sigmoid_fast(aB[2]))
                            | ((unsigned int)f2b(sigmoid_fast(aB[3])) << 16);
            const int wo = (nt * 32 + quad * 8) ^ swz;
            *(uint2*)(SB + hb0 + wo) = make_uint2(a0, a1);
            *(uint2*)(SB + hb1 + wo) = make_uint2(b0, b1);
        }
        if (s + 1 < SEQ) { xc00 = xn00; xc01 = xn01; xc10 = xn10; xc11 = xn11; }
        // NO barrier -- H is wave-private, lgkmcnt orders write->read
    }

    // final H fragments (same-wave lgkm ordering)
    bf16x8 h00 = *(const bf16x8*)(SB + r00);
    bf16x8 h01 = *(const bf16x8*)(SB + r01);
    bf16x8 h10 = *(const bf16x8*)(SB + r10);
    bf16x8 h11 = *(const bf16x8*)(SB + r11);

    // ---- restage: out_w (40KB) into dead weight region, outb into bsum ----
    __syncthreads();    // barrier #2: weight + bsum regions now dead
    for (int c = wv; c < 40; c += 8)
        async16(wsb + WS_OW + c * 512 + lane * 8, &SL[c * 512]);
    {
        const unsigned short* ob = (const unsigned short*)outb;
        if (wv == 3)               async16(ob + lane * 8,       &SL[BSOFF]);
        if (wv == 4 && lane < 11)  async16(ob + 512 + lane * 8, &SL[BSOFF + 512]);
    }
    __syncthreads();    // barrier #3: projection data staged

    const float* OBf = (const float*)&SL[BSOFF];
    float* orow0 = out + brow0 * ANUM;
    float* orow1 = out + brow1 * ANUM;

    #pragma unroll
    for (int t = 0; t < 19; ++t) {     // 19 x 16-col tiles cover 304 cols
        const int cc = t >> 2, nt = t & 3;
        const unsigned short* Of = &SL[cc * 4096 + nt * 1024 + lane * 8];
        bf16x8 a0 = *(const bf16x8*)Of;
        bf16x8 a1 = *(const bf16x8*)(Of + 512);
        const int col0 = cc * 64 + nt * 16 + quad * 4;

        f32x4 bias;
        if (col0 < ANUM) bias = *(const f32x4*)(OBf + col0);
        else             bias = (f32x4){0.f, 0.f, 0.f, 0.f};
        f32x4 aA = bias, aB = bias;
        aA = MFMA(a0, h00, aA, 0, 0, 0);
        aA = MFMA(a1, h01, aA, 0, 0, 0);
        aB = MFMA(a0, h10, aB, 0, 0, 0);
        aB = MFMA(a1, h11, aB, 0, 0, 0);

        if (col0 < ANUM) {             // col0 mult of 4, ANUM=300 mult of 4
            *(f32x4*)(orow0 + col0) = aA;   // plain stores: L2-coalesced
            *(f32x4*)(orow1 + col0) = aB;
        }
    }
}

extern "C" void kernel_launch(void* const* d_in, const int* in_sizes, int n_in,
                              void* d_out, int out_size, void* d_ws, size_t ws_size,
                              hipStream_t stream) {
    const int*   acts = (const int*)  d_in[0];
    const float* emb  = (const float*)d_in[1];
    const float* Mw   = (const float*)d_in[2];
    const float* Mb   = (const float*)d_in[3];
    const float* Ww   = (const float*)d_in[4];
    const float* Wb   = (const float*)d_in[5];
    const float* outw = (const float*)d_in[6];
    const float* outb = (const float*)d_in[7];
    float* out = (float*)d_out;
    (void)in_sizes; (void)n_in; (void)ws_size; (void)out_size;

    unsigned short* wsb = (unsigned short*)d_ws;
    float* bsum = (float*)((char*)d_ws + WS_BSUM_BYTES);

    prepack<<<(PP_TOTAL + 255) / 256, 256, 0, stream>>>(Mw, Ww, outw, emb, Mb, Wb, wsb, bsum);
    carnn_main<<<65536 / 256, 512, 0, stream>>>(acts, wsb, bsum, outb, out);
}

// Round 9
// 119.923 us; speedup vs baseline: 1.0237x; 1.0237x over previous
//
#include <hip/hip_runtime.h>
#include <hip/hip_bf16.h>

// CARNN: 9-step RNN (D=64) + projection to 300 actions, BATCH=65536.
// R13: R12 pipeline with the two correctness risks removed.
// (1) v_cvt_pk_bf16_f32 asm REVERTED to the known-good f2b pair (m240:
//     hand-written cvt_pk is slower anyway; absmax 0.38 suggests its
//     semantics don't bit-match f2b).
// (2) asm volatile("" ::: "memory") fence after each step's H-writes:
//     H is written as uint2 and read as short8 via char* offsets -- TBAA
//     may see no-alias and let the scheduler hoist next step's H ds_read
//     ABOVE the write under R12's reordering pressure. The fence is
//     compile-time only (0 instructions), pins the order; the xacc
//     recompute after it still fills the write->read roundtrip.
// Kept from R12: step s+1's x-GEMM (bias + M*x) computed after step s's
// H-write; x-frags prefetched 2 ahead; R9 geometry (1024 thr, 16 waves x
// 16 rows, grid 256); barrier-free RNN; wave-private XOR-swizzled H;
// projection restaged to LDS; 3 barriers total.

#define SEQ     9
#define DMODEL  64
#define ANUM    300

// ws layout (bf16 element offsets) -- unchanged, prepack identical
#define WS_MW   0        // 9*8192: per step [kind(M=0,W=1)][nt][kb][lane][8]
#define WS_OW   73728    // 5*4096: [cc][nt][kb][lane][8]
#define WS_EMB  94208    // 301*64 bf16 emb table
#define WS_END  113472
#define WS_BSUM_BYTES (WS_END * 2)

// LDS layout (shorts): weights s0M(4096) + s1..7(7*8192) | bsum | scratch
#define BSOFF   61440
#define HSOFF   62592     // 16 waves x 1024 shorts (2KB each)
#define SLTOT   78976     // 157,952 bytes

typedef __attribute__((ext_vector_type(8))) short  bf16x8;
typedef __attribute__((ext_vector_type(4))) float  f32x4;

#define MFMA __builtin_amdgcn_mfma_f32_16x16x32_bf16

__device__ __forceinline__ unsigned short f2b(float f) {
    union { float f; unsigned int u; } x; x.f = f;
    unsigned int r = x.u + 0x7FFFu + ((x.u >> 16) & 1u);
    return (unsigned short)(r >> 16);
}

__device__ __forceinline__ float sigmoid_fast(float v) {
    return __builtin_amdgcn_rcpf(1.f + __expf(-v));
}

// async global->LDS, 16 B per lane; lds base must be wave-uniform
__device__ __forceinline__ void async16(const unsigned short* g, unsigned short* l) {
    __builtin_amdgcn_global_load_lds(
        (const __attribute__((address_space(1))) unsigned int*)g,
        (__attribute__((address_space(3))) unsigned int*)l, 16, 0, 0);
}

// ---------------- pre-pass: convert + pack (unchanged) ----------------
#define PP_TOTAL (73728 + 20480 + 19264 + 576)

__global__ void prepack(const float* __restrict__ Mw, const float* __restrict__ Ww,
                        const float* __restrict__ outw, const float* __restrict__ emb,
                        const float* __restrict__ Mb, const float* __restrict__ Wb,
                        unsigned short* __restrict__ wsb, float* __restrict__ bsum)
{
    int t = blockIdx.x * 256 + threadIdx.x;
    if (t < 73728) {                       // M+W, step-major 16KB blocks
        int s    = t >> 13;
        int r    = t & 8191;
        int kind = r >> 12;
        int f    = r & 4095;
        int nt   = f >> 10;
        int kb   = (f >> 9) & 1;
        int lane = (f >> 3) & 63;
        int j    = f & 7;
        int nr   = nt * 16 + (lane & 15);
        int k    = kb * 32 + ((lane >> 4) << 3) + j;
        const float* src = kind ? Ww : Mw;
        wsb[WS_MW + t] = f2b(src[(s * DMODEL + nr) * DMODEL + k]);
        return;
    }
    t -= 73728;
    if (t < 20480) {                       // outw fragments
        int j    = t & 7;
        int lane = (t >> 3) & 63;
        int kb   = (t >> 9) & 1;
        int nt   = (t >> 10) & 3;
        int cc   = t >> 12;
        int col  = cc * 64 + nt * 16 + (lane & 15);
        int k    = kb * 32 + ((lane >> 4) << 3) + j;
        float v  = (col < ANUM) ? outw[col * DMODEL + k] : 0.f;
        wsb[WS_OW + t] = f2b(v);
        return;
    }
    t -= 20480;
    if (t < 19264) { wsb[WS_EMB + t] = f2b(emb[t]); return; }
    t -= 19264;
    if (t < 576)   { bsum[t] = Mb[t] + Wb[t]; }
}

// ---------------- main ----------------
__global__ __launch_bounds__(1024, 4)
void carnn_main(const int* __restrict__ acts,
                const unsigned short* __restrict__ wsb,
                const float* __restrict__ bsum,
                const float* __restrict__ outb,
                float* __restrict__ out)
{
    __shared__ __align__(16) unsigned short SL[SLTOT];

    const int tid  = threadIdx.x;
    const int lane = tid & 63;
    const int wv   = tid >> 6;         // 0..15
    const int lrow = lane & 15;        // batch row within wave (B-operand n)
    const int quad = lane >> 4;

    const int brow = (blockIdx.x * 16 + wv) * 16 + lrow;   // global batch row
    const int rowS = brow * SEQ;

    // ---- stage weights s0M + s1..7 (120 chunks of 1KB) ----
    for (int c = wv; c < 120; c += 16) {
        const int goff = (c < 8) ? (c * 512) : ((c + 8) * 512);
        async16(wsb + WS_MW + goff + lane * 8, &SL[c * 512]);
    }
    // ---- stage bsum (2304 B) ----
    {
        const unsigned short* bs = (const unsigned short*)bsum;
        if (wv == 13) async16(bs + lane * 8,         &SL[BSOFF]);
        if (wv == 14) async16(bs + 512 + lane * 8,   &SL[BSOFF + 512]);
        if (wv == 15 && lane < 16)
                      async16(bs + 1024 + lane * 8,  &SL[BSOFF + 1024]);
    }

    // x-fragment pipeline: xc = x(0), xn = x(1); idn2 walks id(s+2)
    const unsigned short* Eb = wsb + WS_EMB;
    int id0  = acts[rowS];
    int id1  = acts[rowS + 1];
    int idn2 = acts[rowS + 2];
    bf16x8 xc0 = *(const bf16x8*)(Eb + id0 * DMODEL + quad * 8);
    bf16x8 xc1 = *(const bf16x8*)(Eb + id0 * DMODEL + 32 + quad * 8);
    bf16x8 xn0 = *(const bf16x8*)(Eb + id1 * DMODEL + quad * 8);
    bf16x8 xn1 = *(const bf16x8*)(Eb + id1 * DMODEL + 32 + quad * 8);

    // per-wave H scratch: 2KB, XOR-swizzled (conflict-free b64 w / b128 r)
    char* const SB = (char*)SL;
    const int swz    = (lrow & 7) << 4;
    const int hbyte  = HSOFF * 2 + wv * 2048 + lrow * 128;
    const int rbyte0 = hbyte + ((quad * 16) ^ swz);          // kb0
    const int rbyte1 = hbyte + ((64 + quad * 16) ^ swz);     // kb1

    __syncthreads();    // barrier #1: weights + bsum staged

    const float* BSf = (const float*)&SL[BSOFF];

    // ---- prologue: xacc = bias(0) + M0·x(0) ----
    f32x4 xacc[4];
    #pragma unroll
    for (int nt = 0; nt < 4; ++nt) {
        const unsigned short* Mf = &SL[nt * 1024 + lane * 8];
        bf16x8 am0 = *(const bf16x8*)Mf;
        bf16x8 am1 = *(const bf16x8*)(Mf + 512);
        f32x4 a = *(const f32x4*)(BSf + nt * 16 + quad * 4);
        a = MFMA(am0, xc0, a, 0, 0, 0);
        a = MFMA(am1, xc1, a, 0, 0, 0);
        xacc[nt] = a;
    }

    #pragma unroll
    for (int s = 0; s < SEQ; ++s) {
        // prefetch x(s+2) fragments (covered by this whole step)
        bf16x8 xm0, xm1;
        if (s + 2 < SEQ) {
            xm0 = *(const bf16x8*)(Eb + idn2 * DMODEL + quad * 8);
            xm1 = *(const bf16x8*)(Eb + idn2 * DMODEL + 32 + quad * 8);
            if (s + 3 < SEQ) idn2 = acts[rowS + s + 3];
        }

        // H-dependent half: acc = xacc (+ W(s)·h), sigmoid, pack, write
        bf16x8 h0, h1;
        if (s > 0) {
            h0 = *(const bf16x8*)(SB + rbyte0);
            h1 = *(const bf16x8*)(SB + rbyte1);
        }
        const unsigned short* WBh = (s == 0) ? (const unsigned short*)nullptr
                                  : (s < 8)  ? &SL[4096 + (s - 1) * 8192 + 4096]
                                             : wsb + WS_MW + 8 * 8192 + 4096;
        #pragma unroll
        for (int nt = 0; nt < 4; ++nt) {
            f32x4 acc = xacc[nt];
            if (s > 0) {
                const unsigned short* Wf = WBh + nt * 1024 + lane * 8;
                bf16x8 aw0 = *(const bf16x8*)Wf;
                bf16x8 aw1 = *(const bf16x8*)(Wf + 512);
                acc = MFMA(aw0, h0, acc, 0, 0, 0);
                acc = MFMA(aw1, h1, acc, 0, 0, 0);
            }
            unsigned int u0 = (unsigned int)f2b(sigmoid_fast(acc[0]))
                            | ((unsigned int)f2b(sigmoid_fast(acc[1])) << 16);
            unsigned int u1 = (unsigned int)f2b(sigmoid_fast(acc[2]))
                            | ((unsigned int)f2b(sigmoid_fast(acc[3])) << 16);
            *(uint2*)(SB + hbyte + ((nt * 32 + quad * 8) ^ swz)) = make_uint2(u0, u1);
        }
        // compile-time fence: forbid hoisting next step's H ds_read above
        // the H ds_write (uint2-store vs short8-load TBAA can claim
        // no-alias). Emits no instructions; DS pipe is in-order per wave.
        asm volatile("" ::: "memory");

        // H-independent half of step s+1: xacc = bias(s+1) + M(s+1)·x(s+1)
        // -- fills the H write->read roundtrip with real MFMA work
        if (s + 1 < SEQ) {
            const unsigned short* WBm = (s + 1 < 8) ? &SL[4096 + s * 8192]
                                                    : wsb + WS_MW + 8 * 8192;
            #pragma unroll
            for (int nt = 0; nt < 4; ++nt) {
                const unsigned short* Mf = WBm + nt * 1024 + lane * 8;
                bf16x8 am0 = *(const bf16x8*)Mf;
                bf16x8 am1 = *(const bf16x8*)(Mf + 512);
                f32x4 a = *(const f32x4*)(BSf + (s + 1) * 64 + nt * 16 + quad * 4);
                a = MFMA(am0, xn0, a, 0, 0, 0);
                a = MFMA(am1, xn1, a, 0, 0, 0);
                xacc[nt] = a;
            }
            if (s + 2 < SEQ) { xn0 = xm0; xn1 = xm1; }
        }
        // NO barrier -- H is wave-private, lgkmcnt orders write->read
    }

    // final H fragments (same-wave lgkm ordering; fence above pins order)
    bf16x8 h0 = *(const bf16x8*)(SB + rbyte0);
    bf16x8 h1 = *(const bf16x8*)(SB + rbyte1);

    // ---- restage: out_w (40KB) into dead weight region, outb into bsum ----
    __syncthreads();    // barrier #2: weight + bsum regions now dead
    for (int c = wv; c < 40; c += 16)
        async16(wsb + WS_OW + c * 512 + lane * 8, &SL[c * 512]);
    {
        const unsigned short* ob = (const unsigned short*)outb;
        if (wv == 12)               async16(ob + lane * 8,       &SL[BSOFF]);
        if (wv == 13 && lane < 11)  async16(ob + 512 + lane * 8, &SL[BSOFF + 512]);
    }
    __syncthreads();    // barrier #3: projection data staged

    const float* OBf = (const float*)&SL[BSOFF];
    float* orow = out + brow * ANUM;   // lane's batch row

    #pragma unroll
    for (int t = 0; t < 19; ++t) {     // 19 x 16-col tiles cover 304 cols
        const int cc = t >> 2, nt = t & 3;
        const unsigned short* Of = &SL[cc * 4096 + nt * 1024 + lane * 8];
        bf16x8 a0 = *(const bf16x8*)Of;
        bf16x8 a1 = *(const bf16x8*)(Of + 512);
        const int col0 = cc * 64 + nt * 16 + quad * 4;

        f32x4 acc;
        if (col0 < ANUM) acc = *(const f32x4*)(OBf + col0);
        else             acc = (f32x4){0.f, 0.f, 0.f, 0.f};
        acc = MFMA(a0, h0, acc, 0, 0, 0);
        acc = MFMA(a1, h1, acc, 0, 0, 0);

        if (col0 < ANUM)               // col0 mult of 4, ANUM=300 mult of 4
            *(f32x4*)(orow + col0) = acc;   // plain store: L2-coalesced
    }
}

extern "C" void kernel_launch(void* const* d_in, const int* in_sizes, int n_in,
                              void* d_out, int out_size, void* d_ws, size_t ws_size,
                              hipStream_t stream) {
    const int*   acts = (const int*)  d_in[0];
    const float* emb  = (const float*)d_in[1];
    const float* Mw   = (const float*)d_in[2];
    const float* Mb   = (const float*)d_in[3];
    const float* Ww   = (const float*)d_in[4];
    const float* Wb   = (const float*)d_in[5];
    const float* outw = (const float*)d_in[6];
    const float* outb = (const float*)d_in[7];
    float* out = (float*)d_out;
    (void)in_sizes; (void)n_in; (void)ws_size; (void)out_size;

    unsigned short* wsb = (unsigned short*)d_ws;
    float* bsum = (float*)((char*)d_ws + WS_BSUM_BYTES);

    prepack<<<(PP_TOTAL + 255) / 256, 256, 0, stream>>>(Mw, Ww, outw, emb, Mb, Wb, wsb, bsum);
    carnn_main<<<65536 / 256, 1024, 0, stream>>>(acts, wsb, bsum, outb, out);
}